// Round 7
// baseline (243.149 us; speedup 1.0000x reference)
//
#include <hip/hip_runtime.h>
#include <hip/hip_bf16.h>

// MultiHeadAttention: B=2, S=2048, D=1024, H=16, DH=64, causal, eval-mode.
// f32 I/O, bf16 MFMA internally.
// R7: attn is LDS-BW-bound (m134 model matches measured 56us). Fix: 32 q-rows
//     per wave (128/block) so each K/V fragment read is amortized over 2x the
//     q-rows: 160KB -> 96KB LDS traffic per 128q x 64k. Grid 512 heavy-first.

typedef short bf16x8 __attribute__((ext_vector_type(8)));
typedef float f32x4  __attribute__((ext_vector_type(4)));
typedef short s16x4  __attribute__((ext_vector_type(4)));

#define BB 2
#define SS 2048
#define DD 1024
#define HH 16
#define DHH 64

__device__ __forceinline__ unsigned short f2bf(float f) {
    unsigned u = __builtin_bit_cast(unsigned, f);
    u += 0x7FFFu + ((u >> 16) & 1u);      // RNE
    return (unsigned short)(u >> 16);
}
__device__ __forceinline__ unsigned short f2bf_trunc(float f) {
    return (unsigned short)(__builtin_bit_cast(unsigned, f) >> 16);
}
// async 16B global -> LDS (dest = wave-uniform base + lane*16B)
__device__ __forceinline__ void cp16(const unsigned short* g, unsigned short* l) {
    __builtin_amdgcn_global_load_lds(
        (const __attribute__((address_space(1))) unsigned int*)(g),
        (__attribute__((address_space(3))) unsigned int*)(l), 16, 0, 0);
}

// ---------------------------------------------------------------- f32 -> bf16
__global__ __launch_bounds__(256) void cvt_bf16(
    const float* __restrict__ src, unsigned short* __restrict__ dst, int n) {
    int i = (blockIdx.x * 256 + threadIdx.x) * 4;
    if (i >= n) return;
    float4 v = *reinterpret_cast<const float4*>(src + i);
    s16x4 p;
    p[0] = (short)f2bf(v.x); p[1] = (short)f2bf(v.y);
    p[2] = (short)f2bf(v.z); p[3] = (short)f2bf(v.w);
    *reinterpret_cast<s16x4*>(dst + i) = p;
}

// ---------------------------------------------------------------- transpose
__global__ __launch_bounds__(256) void transpose_w(
    const float* __restrict__ w0, const float* __restrict__ w1,
    const float* __restrict__ w2, const float* __restrict__ w3,
    unsigned short* __restrict__ dst) {
    __shared__ float tile[64][65];
    const float* src = blockIdx.z == 0 ? w0 : blockIdx.z == 1 ? w1
                     : blockIdx.z == 2 ? w2 : w3;
    unsigned short* out = dst + (size_t)blockIdx.z * (DD * DD);
    int bx = blockIdx.x * 64, by = blockIdx.y * 64;
    int tx = threadIdx.x, ty = threadIdx.y;          // block (64,4)
    #pragma unroll
    for (int i = 0; i < 64; i += 4)
        tile[ty + i][tx] = src[(size_t)(by + ty + i) * DD + bx + tx];
    __syncthreads();
    #pragma unroll
    for (int i = 0; i < 64; i += 4)
        out[(size_t)(bx + ty + i) * DD + by + tx] = f2bf(tile[tx][ty + i]);
}

// ---------------------------------------------------------------- QKV GEMM
// C[4096x3072] = A @ Wt^T (+bias). 128x128 tile, BK=64, 4 waves (2x2).
__global__ __launch_bounds__(256) void gemm_qkv(
    const unsigned short* __restrict__ A, const unsigned short* __restrict__ Wt,
    const float* __restrict__ b0, const float* __restrict__ b1,
    const float* __restrict__ b2,
    unsigned short* __restrict__ d0, unsigned short* __restrict__ d1,
    unsigned short* __restrict__ d2) {
    __shared__ __align__(16) unsigned short As[128 * 64];
    __shared__ __align__(16) unsigned short Bs[128 * 64];

    const int tid  = threadIdx.x;
    const int lane = tid & 63;
    const int w    = tid >> 6;
    const int col  = lane & 15;
    const int quad = lane >> 4;
    const int wm   = (w >> 1) * 64;
    const int wn   = (w & 1) * 64;
    const int mb   = blockIdx.y * 128;
    const int nb   = blockIdx.x * 128;

    const int r8 = lane >> 3, gg = lane & 7;
    const int srcoff = ((gg ^ r8) * 8);          // source k-group swizzle
    const int cswz = col & 7;                    // frag-read unswizzle key

    f32x4 acc[4][4];
    #pragma unroll
    for (int i = 0; i < 4; i++)
        #pragma unroll
        for (int j = 0; j < 4; j++) acc[i][j] = (f32x4){0.f, 0.f, 0.f, 0.f};

    for (int kt = 0; kt < 1024; kt += 64) {
        __syncthreads();
        #pragma unroll
        for (int it = 0; it < 4; it++) {
            int row = w * 32 + it * 8 + r8;      // row&7 == r8
            cp16(A  + (size_t)(mb + row) * 1024 + kt + srcoff, As + (w * 32 + it * 8) * 64);
            cp16(Wt + (size_t)(nb + row) * 1024 + kt + srcoff, Bs + (w * 32 + it * 8) * 64);
        }
        __syncthreads();
        #pragma unroll
        for (int kk = 0; kk < 64; kk += 32) {
            const int kg = (kk >> 3) + quad;
            const int pos = ((kg ^ cswz) * 8);
            bf16x8 af[4], bfr[4];
            #pragma unroll
            for (int i = 0; i < 4; i++)
                af[i] = *reinterpret_cast<const bf16x8*>(As + (wm + i * 16 + col) * 64 + pos);
            #pragma unroll
            for (int j = 0; j < 4; j++)
                bfr[j] = *reinterpret_cast<const bf16x8*>(Bs + (wn + j * 16 + col) * 64 + pos);
            #pragma unroll
            for (int i = 0; i < 4; i++)
                #pragma unroll
                for (int j = 0; j < 4; j++)
                    acc[i][j] = __builtin_amdgcn_mfma_f32_16x16x32_bf16(af[i], bfr[j], acc[i][j], 0, 0, 0);
        }
    }

    const float QSCALE = 0.125f * 1.44269504f;   // 1/sqrt(DH) * log2(e)
    #pragma unroll
    for (int i = 0; i < 4; i++) {
        int mg = mb + wm + i * 16 + quad * 4;    // C row = quad*4+reg
        #pragma unroll
        for (int j = 0; j < 4; j++) {
            int ng = nb + wn + j * 16 + col;     // C col = lane&15
            int sel = ng >> 10, n2 = ng & 1023;
            int h = n2 >> 6, dd2 = n2 & 63;
            int b = mg >> 11, s = mg & 2047;
            int bh = b * HH + h;
            const float* bp = sel == 0 ? b0 : sel == 1 ? b1 : b2;
            float bbv = bp[n2];
            if (sel == 0) {          // Q (pre-scaled for exp2 softmax)
                #pragma unroll
                for (int r = 0; r < 4; r++)
                    d0[((size_t)bh * SS + s + r) * DHH + dd2] = f2bf((acc[i][j][r] + bbv) * QSCALE);
            } else if (sel == 1) {   // K
                #pragma unroll
                for (int r = 0; r < 4; r++)
                    d1[((size_t)bh * SS + s + r) * DHH + dd2] = f2bf(acc[i][j][r] + bbv);
            } else {                 // V^T [b][h][d][s]
                s16x4 pack;
                #pragma unroll
                for (int r = 0; r < 4; r++) pack[r] = (short)f2bf(acc[i][j][r] + bbv);
                *reinterpret_cast<s16x4*>(d2 + ((size_t)bh * DHH + dd2) * SS + s) = pack;
            }
        }
    }
}

// ---------------------------------------------------------------- out GEMM
// C[4096x1024] = A @ Wt^T + b, f32 out. 128x64 tile, BK=64, 4 waves (2x2).
__global__ __launch_bounds__(256) void gemm_out(
    const unsigned short* __restrict__ A, const unsigned short* __restrict__ Wt,
    const float* __restrict__ b0, float* __restrict__ d0f) {
    __shared__ __align__(16) unsigned short As[128 * 64];
    __shared__ __align__(16) unsigned short Bs[64 * 64];

    const int tid  = threadIdx.x;
    const int lane = tid & 63;
    const int w    = tid >> 6;
    const int col  = lane & 15;
    const int quad = lane >> 4;
    const int wm   = (w >> 1) * 64;
    const int wn   = (w & 1) * 32;
    const int mb   = blockIdx.y * 128;
    const int nb   = blockIdx.x * 64;

    const int r8 = lane >> 3, gg = lane & 7;
    const int srcoff = ((gg ^ r8) * 8);
    const int cswz = col & 7;

    f32x4 acc[4][2];
    #pragma unroll
    for (int i = 0; i < 4; i++)
        #pragma unroll
        for (int j = 0; j < 2; j++) acc[i][j] = (f32x4){0.f, 0.f, 0.f, 0.f};

    for (int kt = 0; kt < 1024; kt += 64) {
        __syncthreads();
        #pragma unroll
        for (int it = 0; it < 4; it++) {
            int row = w * 32 + it * 8 + r8;
            cp16(A + (size_t)(mb + row) * 1024 + kt + srcoff, As + (w * 32 + it * 8) * 64);
        }
        cp16(Wt + (size_t)(nb + w * 16 + r8) * 1024 + kt + srcoff, Bs + (w * 16) * 64);
        cp16(Wt + (size_t)(nb + w * 16 + 8 + r8) * 1024 + kt + srcoff, Bs + (w * 16 + 8) * 64);
        __syncthreads();
        #pragma unroll
        for (int kk = 0; kk < 64; kk += 32) {
            const int kg = (kk >> 3) + quad;
            const int pos = ((kg ^ cswz) * 8);
            bf16x8 af[4], bfr[2];
            #pragma unroll
            for (int i = 0; i < 4; i++)
                af[i] = *reinterpret_cast<const bf16x8*>(As + (wm + i * 16 + col) * 64 + pos);
            #pragma unroll
            for (int j = 0; j < 2; j++)
                bfr[j] = *reinterpret_cast<const bf16x8*>(Bs + (wn + j * 16 + col) * 64 + pos);
            #pragma unroll
            for (int i = 0; i < 4; i++)
                #pragma unroll
                for (int j = 0; j < 2; j++)
                    acc[i][j] = __builtin_amdgcn_mfma_f32_16x16x32_bf16(af[i], bfr[j], acc[i][j], 0, 0, 0);
        }
    }

    #pragma unroll
    for (int i = 0; i < 4; i++) {
        int mg = mb + wm + i * 16 + quad * 4;
        #pragma unroll
        for (int j = 0; j < 2; j++) {
            int ng = nb + wn + j * 16 + col;
            float bbv = b0[ng];
            #pragma unroll
            for (int r = 0; r < 4; r++)
                d0f[(size_t)(mg + r) * 1024 + ng] = acc[i][j][r] + bbv;
        }
    }
}

// ---------------------------------------------------------------- attention
// 512 blocks: bh = bx&31, qt = 15-(bx>>5) (heavy first). 4 waves x 32 q-rows
// (two 16-row A-frags/wave): K/V fragment reads amortized over 2x q-rows.
// Key tiles of 64, staged in pairs (ntiles = 2qt+2, always even). Softmax per
// tile; row sums via ones-fragment MFMA (l); truncating P conversion.
__global__ __launch_bounds__(256) void attn(
    const unsigned short* __restrict__ Q, const unsigned short* __restrict__ K,
    const unsigned short* __restrict__ Vt, unsigned short* __restrict__ O) {
    __shared__ __align__(16) unsigned short Ks[2][64 * 64];  // [key][dh] swizzled
    __shared__ __align__(16) unsigned short Vs[2][64 * 64];  // [dh][key] swizzled
    __shared__ __align__(16) unsigned short Ps[4][32 * 72];  // per-wave P [m][k]

    const int tid  = threadIdx.x;
    const int lane = tid & 63;
    const int w    = tid >> 6;
    const int col  = lane & 15;
    const int quad = lane >> 4;
    const int bh   = blockIdx.x & 31;
    const int qt   = 15 - (blockIdx.x >> 5);   // heavy first
    const int qb   = qt * 128;
    const int wq   = qb + w * 32;              // wave's 32 q-rows
    const int r8 = lane >> 3, gg = lane & 7;
    const int srcoff = ((gg ^ r8) * 8);
    const int cswz = col & 7;
    const int pos0 = (quad       ^ cswz) * 8;  // loop-invariant frag offsets
    const int pos1 = ((4 + quad) ^ cswz) * 8;

    bf16x8 onesf;                               // B-frag: virtual V col of 1s
    #pragma unroll
    for (int j = 0; j < 8; j++) onesf[j] = (col == 0) ? (short)0x3F80 : (short)0;

    const size_t qb0 = ((size_t)bh * SS + wq + col) * DHH;
    const size_t qb1 = ((size_t)bh * SS + wq + 16 + col) * DHH;
    bf16x8 qf[2][2];                            // [sub][lo/hi]
    qf[0][0] = *reinterpret_cast<const bf16x8*>(Q + qb0 + quad * 8);
    qf[0][1] = *reinterpret_cast<const bf16x8*>(Q + qb0 + 32 + quad * 8);
    qf[1][0] = *reinterpret_cast<const bf16x8*>(Q + qb1 + quad * 8);
    qf[1][1] = *reinterpret_cast<const bf16x8*>(Q + qb1 + 32 + quad * 8);

    f32x4 o[2][4], l[2];
    #pragma unroll
    for (int s = 0; s < 2; s++) {
        l[s] = (f32x4){0.f, 0.f, 0.f, 0.f};
        #pragma unroll
        for (int d = 0; d < 4; d++) o[s][d] = (f32x4){0.f, 0.f, 0.f, 0.f};
    }
    float m_i[2][4];
    #pragma unroll
    for (int s = 0; s < 2; s++)
        #pragma unroll
        for (int r = 0; r < 4; r++) m_i[s][r] = -1e30f;

    const int ntiles = 2 * qt + 2;             // always even
    for (int t0 = 0; t0 < ntiles; t0 += 2) {
        __syncthreads();                       // WAR on Ks/Vs
        #pragma unroll
        for (int it = 0; it < 2; it++) {       // stage both tiles of the pair
            int row = w * 16 + it * 8 + r8;    // row&7 == r8
            cp16(K  + ((size_t)bh * SS + t0 * 64 + row) * DHH + srcoff,
                 Ks[0] + (w * 16 + it * 8) * 64);
            cp16(Vt + ((size_t)bh * DHH + row) * SS + t0 * 64 + srcoff,
                 Vs[0] + (w * 16 + it * 8) * 64);
            cp16(K  + ((size_t)bh * SS + (t0 + 1) * 64 + row) * DHH + srcoff,
                 Ks[1] + (w * 16 + it * 8) * 64);
            cp16(Vt + ((size_t)bh * DHH + row) * SS + (t0 + 1) * 64 + srcoff,
                 Vs[1] + (w * 16 + it * 8) * 64);
        }
        __syncthreads();

        #pragma unroll
        for (int tt = 0; tt < 2; tt++) {
            const int ktg = t0 + tt;
            // ---- scores: 32 q-rows x 64 keys; K-frags shared across subs
            f32x4 sc[2][4];
            #pragma unroll
            for (int nt = 0; nt < 4; nt++) {
                int key = nt * 16 + col;
                bf16x8 klo = *reinterpret_cast<const bf16x8*>(Ks[tt] + key * 64 + pos0);
                bf16x8 khi = *reinterpret_cast<const bf16x8*>(Ks[tt] + key * 64 + pos1);
                f32x4 z0 = (f32x4){0.f, 0.f, 0.f, 0.f};
                f32x4 z1 = (f32x4){0.f, 0.f, 0.f, 0.f};
                z0 = __builtin_amdgcn_mfma_f32_16x16x32_bf16(qf[0][0], klo, z0, 0, 0, 0);
                z0 = __builtin_amdgcn_mfma_f32_16x16x32_bf16(qf[0][1], khi, z0, 0, 0, 0);
                z1 = __builtin_amdgcn_mfma_f32_16x16x32_bf16(qf[1][0], klo, z1, 0, 0, 0);
                z1 = __builtin_amdgcn_mfma_f32_16x16x32_bf16(qf[1][1], khi, z1, 0, 0, 0);
                sc[0][nt] = z0; sc[1][nt] = z1;
            }
            if (ktg >= 2 * qt) {               // diagonal spans last 2 tiles
                #pragma unroll
                for (int s = 0; s < 2; s++)
                    #pragma unroll
                    for (int nt = 0; nt < 4; nt++) {
                        int kg = ktg * 64 + nt * 16 + col;
                        #pragma unroll
                        for (int r = 0; r < 4; r++) {
                            int qg = wq + s * 16 + quad * 4 + r;
                            if (kg > qg) sc[s][nt][r] = -3.0e38f;
                        }
                    }
            }
            // ---- online softmax update (per sub, per r)
            float mnew[2][4];
            bool upd = false;
            #pragma unroll
            for (int s = 0; s < 2; s++)
                #pragma unroll
                for (int r = 0; r < 4; r++) {
                    float t = fmaxf(fmaxf(sc[s][0][r], sc[s][1][r]),
                                    fmaxf(sc[s][2][r], sc[s][3][r]));
                    t = fmaxf(t, __shfl_xor(t, 1));
                    t = fmaxf(t, __shfl_xor(t, 2));
                    t = fmaxf(t, __shfl_xor(t, 4));
                    t = fmaxf(t, __shfl_xor(t, 8));
                    mnew[s][r] = fmaxf(m_i[s][r], t);
                    upd = upd || (mnew[s][r] > m_i[s][r]);
                }
            if (__any(upd)) {                  // wave-uniform rescale skip
                #pragma unroll
                for (int s = 0; s < 2; s++)
                    #pragma unroll
                    for (int r = 0; r < 4; r++) {
                        float a = exp2f(m_i[s][r] - mnew[s][r]);
                        #pragma unroll
                        for (int d = 0; d < 4; d++) o[s][d][r] *= a;
                        l[s][r] *= a;
                    }
            }
            #pragma unroll
            for (int s = 0; s < 2; s++)
                #pragma unroll
                for (int r = 0; r < 4; r++) m_i[s][r] = mnew[s][r];

            // ---- P: C-layout -> A-layout via per-wave LDS
            unsigned short* pw = Ps[w];
            #pragma unroll
            for (int s = 0; s < 2; s++)
                #pragma unroll
                for (int nt = 0; nt < 4; nt++)
                    #pragma unroll
                    for (int r = 0; r < 4; r++)
                        pw[(s * 16 + quad * 4 + r) * 72 + nt * 16 + col] =
                            f2bf_trunc(exp2f(sc[s][nt][r] - mnew[s][r]));
            bf16x8 pf[2][2];
            #pragma unroll
            for (int s = 0; s < 2; s++) {
                pf[s][0] = *reinterpret_cast<const bf16x8*>(pw + (s * 16 + col) * 72 + quad * 8);
                pf[s][1] = *reinterpret_cast<const bf16x8*>(pw + (s * 16 + col) * 72 + 32 + quad * 8);
            }
            // ---- PV: V-frags shared across subs
            #pragma unroll
            for (int dt = 0; dt < 4; dt++) {
                int rv = dt * 16 + col;
                bf16x8 vf0 = *reinterpret_cast<const bf16x8*>(Vs[tt] + rv * 64 + pos0);
                bf16x8 vf1 = *reinterpret_cast<const bf16x8*>(Vs[tt] + rv * 64 + pos1);
                #pragma unroll
                for (int s = 0; s < 2; s++) {
                    o[s][dt] = __builtin_amdgcn_mfma_f32_16x16x32_bf16(pf[s][0], vf0, o[s][dt], 0, 0, 0);
                    o[s][dt] = __builtin_amdgcn_mfma_f32_16x16x32_bf16(pf[s][1], vf1, o[s][dt], 0, 0, 0);
                }
            }
            #pragma unroll
            for (int s = 0; s < 2; s++) {
                l[s] = __builtin_amdgcn_mfma_f32_16x16x32_bf16(pf[s][0], onesf, l[s], 0, 0, 0);
                l[s] = __builtin_amdgcn_mfma_f32_16x16x32_bf16(pf[s][1], onesf, l[s], 0, 0, 0);
            }
        }
    }

    // epilogue: l lives in lanes col==0; broadcast within 16-lane group
    #pragma unroll
    for (int s = 0; s < 2; s++)
        #pragma unroll
        for (int r = 0; r < 4; r++) {
            float lv = __shfl(l[s][r], lane & 48);
            float inv = 1.0f / lv;
            int sq = wq + s * 16 + quad * 4 + r;
            size_t base = ((size_t)(bh >> 4) * SS + sq) * DD + (size_t)(bh & 15) * DHH;
            #pragma unroll
            for (int dt = 0; dt < 4; dt++)
                O[base + dt * 16 + col] = f2bf(o[s][dt][r] * inv);
        }
}

// ---------------------------------------------------------------- launch
extern "C" void kernel_launch(void* const* d_in, const int* in_sizes, int n_in,
                              void* d_out, int out_size, void* d_ws, size_t ws_size,
                              hipStream_t stream) {
    (void)in_sizes; (void)n_in; (void)out_size; (void)ws_size;
    const float* x  = (const float*)d_in[0];
    const float* Wq = (const float*)d_in[2];
    const float* bq = (const float*)d_in[3];
    const float* Wk = (const float*)d_in[4];
    const float* bk = (const float*)d_in[5];
    const float* Wv = (const float*)d_in[6];
    const float* bv = (const float*)d_in[7];
    const float* Wo = (const float*)d_in[8];
    const float* bo = (const float*)d_in[9];
    float* out = (float*)d_out;

    // ws (40 MB): x_bf/O | Q | K | V^T | Wt x4
    char* ws = (char*)d_ws;
    unsigned short* xbf = (unsigned short*)(ws);
    unsigned short* qws = (unsigned short*)(ws + ((size_t)8  << 20));
    unsigned short* kws = (unsigned short*)(ws + ((size_t)16 << 20));
    unsigned short* vws = (unsigned short*)(ws + ((size_t)24 << 20));
    unsigned short* wt  = (unsigned short*)(ws + ((size_t)32 << 20));
    unsigned short* ows = xbf;   // O overwrites x_bf (dead after QKV GEMM)

    const int nx = BB * SS * DD;               // 4,194,304
    cvt_bf16<<<dim3(nx / 1024), 256, 0, stream>>>(x, xbf, nx);
    transpose_w<<<dim3(16, 16, 4), dim3(64, 4), 0, stream>>>(Wq, Wk, Wv, Wo, wt);
    gemm_qkv<<<dim3(24, 32), 256, 0, stream>>>(xbf, wt, bq, bk, bv,
                                               qws, kws, vws);
    attn<<<dim3(512), 256, 0, stream>>>(qws, kws, vws, ows);
    gemm_out<<<dim3(16, 32), 256, 0, stream>>>(ows, wt + (size_t)3 * 1024 * 1024,
                                               bo, out);
}

// Round 8
// 209.371 us; speedup vs baseline: 1.1613x; 1.1613x over previous
//
#include <hip/hip_runtime.h>
#include <hip/hip_bf16.h>

// MultiHeadAttention: B=2, S=2048, D=1024, H=16, DH=64, causal, eval-mode.
// f32 I/O, bf16 MFMA internally.
// R8: attn reverted to R6 structure (R7's 2x q-rows collapsed occupancy
//     25.8->12.7% and regressed 56->86us). cvt+transpose merged into one
//     prep kernel (5->4 launches; both memory-bound jobs co-run).

typedef short bf16x8 __attribute__((ext_vector_type(8)));
typedef float f32x4  __attribute__((ext_vector_type(4)));
typedef short s16x4  __attribute__((ext_vector_type(4)));

#define BB 2
#define SS 2048
#define DD 1024
#define HH 16
#define DHH 64

__device__ __forceinline__ unsigned short f2bf(float f) {
    unsigned u = __builtin_bit_cast(unsigned, f);
    u += 0x7FFFu + ((u >> 16) & 1u);      // RNE
    return (unsigned short)(u >> 16);
}
__device__ __forceinline__ unsigned short f2bf_trunc(float f) {
    return (unsigned short)(__builtin_bit_cast(unsigned, f) >> 16);
}
// async 16B global -> LDS (dest = wave-uniform base + lane*16B)
__device__ __forceinline__ void cp16(const unsigned short* g, unsigned short* l) {
    __builtin_amdgcn_global_load_lds(
        (const __attribute__((address_space(1))) unsigned int*)(g),
        (__attribute__((address_space(3))) unsigned int*)(l), 16, 0, 0);
}

// ---------------------------------------------------------------- prep
// blocks [0,4096): x f32 -> bf16.  blocks [4096,5120): W transpose f32->bf16.
__global__ __launch_bounds__(256) void prep(
    const float* __restrict__ x,
    const float* __restrict__ w0, const float* __restrict__ w1,
    const float* __restrict__ w2, const float* __restrict__ w3,
    unsigned short* __restrict__ xbf, unsigned short* __restrict__ wt) {
    __shared__ float tile[64][65];
    const int bid = blockIdx.x;
    const int tid = threadIdx.x;
    if (bid < 4096) {                          // cvt: 4 elems/thread
        int i = (bid * 256 + tid) * 4;
        float4 v = *reinterpret_cast<const float4*>(x + i);
        s16x4 p;
        p[0] = (short)f2bf(v.x); p[1] = (short)f2bf(v.y);
        p[2] = (short)f2bf(v.z); p[3] = (short)f2bf(v.w);
        *reinterpret_cast<s16x4*>(xbf + i) = p;
        return;
    }
    const int tb = bid - 4096;                 // 0..1023
    const int z  = tb >> 8;                    // matrix 0..3
    const int bx = (tb & 15) * 64, by = ((tb >> 4) & 15) * 64;
    const float* src = z == 0 ? w0 : z == 1 ? w1 : z == 2 ? w2 : w3;
    unsigned short* out = wt + (size_t)z * (DD * DD);
    const int tx = tid & 63, ty = tid >> 6;
    #pragma unroll
    for (int i = 0; i < 64; i += 4)
        tile[ty + i][tx] = src[(size_t)(by + ty + i) * DD + bx + tx];
    __syncthreads();
    #pragma unroll
    for (int i = 0; i < 64; i += 4)
        out[(size_t)(bx + ty + i) * DD + by + tx] = f2bf(tile[tx][ty + i]);
}

// ---------------------------------------------------------------- QKV GEMM
// C[4096x3072] = A @ Wt^T (+bias). 128x128 tile, BK=64, 4 waves (2x2).
// LDS stride 64, k-groups XOR-swizzled by row&7; staging via cp16.
__global__ __launch_bounds__(256) void gemm_qkv(
    const unsigned short* __restrict__ A, const unsigned short* __restrict__ Wt,
    const float* __restrict__ b0, const float* __restrict__ b1,
    const float* __restrict__ b2,
    unsigned short* __restrict__ d0, unsigned short* __restrict__ d1,
    unsigned short* __restrict__ d2) {
    __shared__ __align__(16) unsigned short As[128 * 64];
    __shared__ __align__(16) unsigned short Bs[128 * 64];

    const int tid  = threadIdx.x;
    const int lane = tid & 63;
    const int w    = tid >> 6;
    const int col  = lane & 15;
    const int quad = lane >> 4;
    const int wm   = (w >> 1) * 64;
    const int wn   = (w & 1) * 64;
    const int mb   = blockIdx.y * 128;
    const int nb   = blockIdx.x * 128;

    const int r8 = lane >> 3, gg = lane & 7;
    const int srcoff = ((gg ^ r8) * 8);          // source k-group swizzle
    const int cswz = col & 7;                    // frag-read unswizzle key

    f32x4 acc[4][4];
    #pragma unroll
    for (int i = 0; i < 4; i++)
        #pragma unroll
        for (int j = 0; j < 4; j++) acc[i][j] = (f32x4){0.f, 0.f, 0.f, 0.f};

    for (int kt = 0; kt < 1024; kt += 64) {
        __syncthreads();
        #pragma unroll
        for (int it = 0; it < 4; it++) {
            int row = w * 32 + it * 8 + r8;      // row&7 == r8
            cp16(A  + (size_t)(mb + row) * 1024 + kt + srcoff, As + (w * 32 + it * 8) * 64);
            cp16(Wt + (size_t)(nb + row) * 1024 + kt + srcoff, Bs + (w * 32 + it * 8) * 64);
        }
        __syncthreads();
        #pragma unroll
        for (int kk = 0; kk < 64; kk += 32) {
            const int kg = (kk >> 3) + quad;
            const int pos = ((kg ^ cswz) * 8);
            bf16x8 af[4], bfr[4];
            #pragma unroll
            for (int i = 0; i < 4; i++)
                af[i] = *reinterpret_cast<const bf16x8*>(As + (wm + i * 16 + col) * 64 + pos);
            #pragma unroll
            for (int j = 0; j < 4; j++)
                bfr[j] = *reinterpret_cast<const bf16x8*>(Bs + (wn + j * 16 + col) * 64 + pos);
            #pragma unroll
            for (int i = 0; i < 4; i++)
                #pragma unroll
                for (int j = 0; j < 4; j++)
                    acc[i][j] = __builtin_amdgcn_mfma_f32_16x16x32_bf16(af[i], bfr[j], acc[i][j], 0, 0, 0);
        }
    }

    const float QSCALE = 0.125f * 1.44269504f;   // 1/sqrt(DH) * log2(e)
    #pragma unroll
    for (int i = 0; i < 4; i++) {
        int mg = mb + wm + i * 16 + quad * 4;    // C row = quad*4+reg
        #pragma unroll
        for (int j = 0; j < 4; j++) {
            int ng = nb + wn + j * 16 + col;     // C col = lane&15
            int sel = ng >> 10, n2 = ng & 1023;
            int h = n2 >> 6, dd2 = n2 & 63;
            int b = mg >> 11, s = mg & 2047;
            int bh = b * HH + h;
            const float* bp = sel == 0 ? b0 : sel == 1 ? b1 : b2;
            float bbv = bp[n2];
            if (sel == 0) {          // Q (pre-scaled for exp2 softmax)
                #pragma unroll
                for (int r = 0; r < 4; r++)
                    d0[((size_t)bh * SS + s + r) * DHH + dd2] = f2bf((acc[i][j][r] + bbv) * QSCALE);
            } else if (sel == 1) {   // K
                #pragma unroll
                for (int r = 0; r < 4; r++)
                    d1[((size_t)bh * SS + s + r) * DHH + dd2] = f2bf(acc[i][j][r] + bbv);
            } else {                 // V^T [b][h][d][s]
                s16x4 pack;
                #pragma unroll
                for (int r = 0; r < 4; r++) pack[r] = (short)f2bf(acc[i][j][r] + bbv);
                *reinterpret_cast<s16x4*>(d2 + ((size_t)bh * DHH + dd2) * SS + s) = pack;
            }
        }
    }
}

// ---------------------------------------------------------------- out GEMM
// C[4096x1024] = A @ Wt^T + b, f32 out. 128x64 tile, BK=64, 4 waves (2x2).
__global__ __launch_bounds__(256) void gemm_out(
    const unsigned short* __restrict__ A, const unsigned short* __restrict__ Wt,
    const float* __restrict__ b0, float* __restrict__ d0f) {
    __shared__ __align__(16) unsigned short As[128 * 64];
    __shared__ __align__(16) unsigned short Bs[64 * 64];

    const int tid  = threadIdx.x;
    const int lane = tid & 63;
    const int w    = tid >> 6;
    const int col  = lane & 15;
    const int quad = lane >> 4;
    const int wm   = (w >> 1) * 64;
    const int wn   = (w & 1) * 32;
    const int mb   = blockIdx.y * 128;
    const int nb   = blockIdx.x * 64;

    const int r8 = lane >> 3, gg = lane & 7;
    const int srcoff = ((gg ^ r8) * 8);
    const int cswz = col & 7;

    f32x4 acc[4][2];
    #pragma unroll
    for (int i = 0; i < 4; i++)
        #pragma unroll
        for (int j = 0; j < 2; j++) acc[i][j] = (f32x4){0.f, 0.f, 0.f, 0.f};

    for (int kt = 0; kt < 1024; kt += 64) {
        __syncthreads();
        #pragma unroll
        for (int it = 0; it < 4; it++) {
            int row = w * 32 + it * 8 + r8;
            cp16(A + (size_t)(mb + row) * 1024 + kt + srcoff, As + (w * 32 + it * 8) * 64);
        }
        cp16(Wt + (size_t)(nb + w * 16 + r8) * 1024 + kt + srcoff, Bs + (w * 16) * 64);
        cp16(Wt + (size_t)(nb + w * 16 + 8 + r8) * 1024 + kt + srcoff, Bs + (w * 16 + 8) * 64);
        __syncthreads();
        #pragma unroll
        for (int kk = 0; kk < 64; kk += 32) {
            const int kg = (kk >> 3) + quad;
            const int pos = ((kg ^ cswz) * 8);
            bf16x8 af[4], bfr[2];
            #pragma unroll
            for (int i = 0; i < 4; i++)
                af[i] = *reinterpret_cast<const bf16x8*>(As + (wm + i * 16 + col) * 64 + pos);
            #pragma unroll
            for (int j = 0; j < 2; j++)
                bfr[j] = *reinterpret_cast<const bf16x8*>(Bs + (wn + j * 16 + col) * 64 + pos);
            #pragma unroll
            for (int i = 0; i < 4; i++)
                #pragma unroll
                for (int j = 0; j < 2; j++)
                    acc[i][j] = __builtin_amdgcn_mfma_f32_16x16x32_bf16(af[i], bfr[j], acc[i][j], 0, 0, 0);
        }
    }

    #pragma unroll
    for (int i = 0; i < 4; i++) {
        int mg = mb + wm + i * 16 + quad * 4;
        #pragma unroll
        for (int j = 0; j < 2; j++) {
            int ng = nb + wn + j * 16 + col;
            float bbv = b0[ng];
            #pragma unroll
            for (int r = 0; r < 4; r++)
                d0f[(size_t)(mg + r) * 1024 + ng] = acc[i][j][r] + bbv;
        }
    }
}

// ---------------------------------------------------------------- attention
// 1024 blocks: bh = bx&31, qt = 31-(bx>>5) (heavy first). 4 waves x 16 q-rows.
// 128-key double-tiles: one softmax update per pair. Row sums via
// ones-fragment MFMA (l = o[4]). Truncating P conversion (bias cancels).
__global__ __launch_bounds__(256, 3) void attn(
    const unsigned short* __restrict__ Q, const unsigned short* __restrict__ K,
    const unsigned short* __restrict__ Vt, unsigned short* __restrict__ O) {
    __shared__ __align__(16) unsigned short Ks[2][64 * 64];  // [key][dh] swizzled
    __shared__ __align__(16) unsigned short Vs[2][64 * 64];  // [dh][key] swizzled
    __shared__ __align__(16) unsigned short Ps[4][16 * 72];  // per-wave P [m][k]

    const int tid  = threadIdx.x;
    const int lane = tid & 63;
    const int w    = tid >> 6;
    const int col  = lane & 15;
    const int quad = lane >> 4;
    const int bh   = blockIdx.x & 31;
    const int qt   = 31 - (blockIdx.x >> 5);   // heavy first
    const int qb   = qt * 64;
    const int r8 = lane >> 3, gg = lane & 7;
    const int srcoff = ((gg ^ r8) * 8);
    const int cswz = col & 7;
    const int pos0 = (quad       ^ cswz) * 8;  // loop-invariant frag offsets
    const int pos1 = ((4 + quad) ^ cswz) * 8;

    bf16x8 onesf;                               // B-frag: virtual V col of 1s
    #pragma unroll
    for (int j = 0; j < 8; j++) onesf[j] = (col == 0) ? (short)0x3F80 : (short)0;

    const int qrow = qb + w * 16 + col;
    const size_t qbase = ((size_t)bh * SS + qrow) * DHH;
    bf16x8 qlo = *reinterpret_cast<const bf16x8*>(Q + qbase + quad * 8);
    bf16x8 qhi = *reinterpret_cast<const bf16x8*>(Q + qbase + 32 + quad * 8);

    f32x4 o[5];
    #pragma unroll
    for (int d = 0; d < 5; d++) o[d] = (f32x4){0.f, 0.f, 0.f, 0.f};
    float m_i[4];
    #pragma unroll
    for (int r = 0; r < 4; r++) m_i[r] = -1e30f;

    const int ntiles = qt + 1;
    for (int t0 = 0; t0 < ntiles; t0 += 2) {
        const bool two = (t0 + 1 < ntiles);
        __syncthreads();                       // WAR on Ks/Vs
        #pragma unroll
        for (int it = 0; it < 2; it++) {       // stage sub0: K + V^T (8KB each)
            int row = w * 16 + it * 8 + r8;    // row&7 == r8
            cp16(K  + ((size_t)bh * SS + t0 * 64 + row) * DHH + srcoff,
                 Ks[0] + (w * 16 + it * 8) * 64);
            cp16(Vt + ((size_t)bh * DHH + row) * SS + t0 * 64 + srcoff,
                 Vs[0] + (w * 16 + it * 8) * 64);
        }
        if (two) {
            #pragma unroll
            for (int it = 0; it < 2; it++) {   // stage sub1
                int row = w * 16 + it * 8 + r8;
                cp16(K  + ((size_t)bh * SS + (t0 + 1) * 64 + row) * DHH + srcoff,
                     Ks[1] + (w * 16 + it * 8) * 64);
                cp16(Vt + ((size_t)bh * DHH + row) * SS + (t0 + 1) * 64 + srcoff,
                     Vs[1] + (w * 16 + it * 8) * 64);
            }
        }
        __syncthreads();

        // ---- scores: 16 q-rows x (64 or 128) keys per wave
        f32x4 sc[8];
        #pragma unroll
        for (int nt = 0; nt < 4; nt++) {
            int key = nt * 16 + col;
            bf16x8 klo = *reinterpret_cast<const bf16x8*>(Ks[0] + key * 64 + pos0);
            bf16x8 khi = *reinterpret_cast<const bf16x8*>(Ks[0] + key * 64 + pos1);
            f32x4 z = (f32x4){0.f, 0.f, 0.f, 0.f};
            z = __builtin_amdgcn_mfma_f32_16x16x32_bf16(qlo, klo, z, 0, 0, 0);
            z = __builtin_amdgcn_mfma_f32_16x16x32_bf16(qhi, khi, z, 0, 0, 0);
            sc[nt] = z;
        }
        if (two) {
            #pragma unroll
            for (int nt = 0; nt < 4; nt++) {
                int key = nt * 16 + col;
                bf16x8 klo = *reinterpret_cast<const bf16x8*>(Ks[1] + key * 64 + pos0);
                bf16x8 khi = *reinterpret_cast<const bf16x8*>(Ks[1] + key * 64 + pos1);
                f32x4 z = (f32x4){0.f, 0.f, 0.f, 0.f};
                z = __builtin_amdgcn_mfma_f32_16x16x32_bf16(qlo, klo, z, 0, 0, 0);
                z = __builtin_amdgcn_mfma_f32_16x16x32_bf16(qhi, khi, z, 0, 0, 0);
                sc[4 + nt] = z;
            }
        }
        // causal mask (diagonal tile only; t0==qt implies !two)
        if (t0 == qt || (two && t0 + 1 == qt)) {
            const int sb = (t0 == qt) ? 0 : 4;
            const int tb = (t0 == qt) ? t0 : t0 + 1;
            #pragma unroll
            for (int nt = 0; nt < 4; nt++) {
                int kg = tb * 64 + nt * 16 + col;
                #pragma unroll
                for (int r = 0; r < 4; r++) {
                    int qg = qb + w * 16 + quad * 4 + r;
                    if (kg > qg) sc[sb + nt][r] = -3.0e38f;
                }
            }
        }
        // ---- ONE online-softmax update per 128 keys
        float mnew[4];
        bool upd = false;
        #pragma unroll
        for (int r = 0; r < 4; r++) {
            float t = fmaxf(fmaxf(sc[0][r], sc[1][r]), fmaxf(sc[2][r], sc[3][r]));
            if (two)
                t = fmaxf(t, fmaxf(fmaxf(sc[4][r], sc[5][r]), fmaxf(sc[6][r], sc[7][r])));
            t = fmaxf(t, __shfl_xor(t, 1));
            t = fmaxf(t, __shfl_xor(t, 2));
            t = fmaxf(t, __shfl_xor(t, 4));
            t = fmaxf(t, __shfl_xor(t, 8));
            mnew[r] = fmaxf(m_i[r], t);
            upd = upd || (mnew[r] > m_i[r]);
        }
        if (__any(upd)) {                      // wave-uniform rescale skip
            #pragma unroll
            for (int r = 0; r < 4; r++) {
                float a = exp2f(m_i[r] - mnew[r]);
                #pragma unroll
                for (int d = 0; d < 5; d++) o[d][r] *= a;
            }
        }
        #pragma unroll
        for (int r = 0; r < 4; r++) m_i[r] = mnew[r];

        unsigned short* pw = Ps[w];
        // ---- sub0: P (C-layout -> A-layout via per-wave LDS) + PV
        #pragma unroll
        for (int nt = 0; nt < 4; nt++)
            #pragma unroll
            for (int r = 0; r < 4; r++)
                pw[(quad * 4 + r) * 72 + nt * 16 + col] = f2bf_trunc(exp2f(sc[nt][r] - mnew[r]));
        {
            bf16x8 pf0 = *reinterpret_cast<const bf16x8*>(pw + col * 72 + quad * 8);
            bf16x8 pf1 = *reinterpret_cast<const bf16x8*>(pw + col * 72 + 32 + quad * 8);
            #pragma unroll
            for (int dt = 0; dt < 4; dt++) {
                int rv = dt * 16 + col;
                bf16x8 vf0 = *reinterpret_cast<const bf16x8*>(Vs[0] + rv * 64 + pos0);
                bf16x8 vf1 = *reinterpret_cast<const bf16x8*>(Vs[0] + rv * 64 + pos1);
                o[dt] = __builtin_amdgcn_mfma_f32_16x16x32_bf16(pf0, vf0, o[dt], 0, 0, 0);
                o[dt] = __builtin_amdgcn_mfma_f32_16x16x32_bf16(pf1, vf1, o[dt], 0, 0, 0);
            }
            o[4] = __builtin_amdgcn_mfma_f32_16x16x32_bf16(pf0, onesf, o[4], 0, 0, 0);
            o[4] = __builtin_amdgcn_mfma_f32_16x16x32_bf16(pf1, onesf, o[4], 0, 0, 0);
        }
        // ---- sub1 (same-wave DS ordering makes Ps reuse sync-free)
        if (two) {
            #pragma unroll
            for (int nt = 0; nt < 4; nt++)
                #pragma unroll
                for (int r = 0; r < 4; r++)
                    pw[(quad * 4 + r) * 72 + nt * 16 + col] = f2bf_trunc(exp2f(sc[4 + nt][r] - mnew[r]));
            bf16x8 pf0 = *reinterpret_cast<const bf16x8*>(pw + col * 72 + quad * 8);
            bf16x8 pf1 = *reinterpret_cast<const bf16x8*>(pw + col * 72 + 32 + quad * 8);
            #pragma unroll
            for (int dt = 0; dt < 4; dt++) {
                int rv = dt * 16 + col;
                bf16x8 vf0 = *reinterpret_cast<const bf16x8*>(Vs[1] + rv * 64 + pos0);
                bf16x8 vf1 = *reinterpret_cast<const bf16x8*>(Vs[1] + rv * 64 + pos1);
                o[dt] = __builtin_amdgcn_mfma_f32_16x16x32_bf16(pf0, vf0, o[dt], 0, 0, 0);
                o[dt] = __builtin_amdgcn_mfma_f32_16x16x32_bf16(pf1, vf1, o[dt], 0, 0, 0);
            }
            o[4] = __builtin_amdgcn_mfma_f32_16x16x32_bf16(pf0, onesf, o[4], 0, 0, 0);
            o[4] = __builtin_amdgcn_mfma_f32_16x16x32_bf16(pf1, onesf, o[4], 0, 0, 0);
        }
    }

    // epilogue: l lives in o[4][r] of lanes col==0; broadcast within quad
    #pragma unroll
    for (int r = 0; r < 4; r++) {
        float lv = __shfl(o[4][r], lane & 48);
        float inv = 1.0f / lv;
        int sq = qb + w * 16 + quad * 4 + r;
        size_t base = ((size_t)(bh >> 4) * SS + sq) * DD + (size_t)(bh & 15) * DHH;
        #pragma unroll
        for (int dt = 0; dt < 4; dt++)
            O[base + dt * 16 + col] = f2bf(o[dt][r] * inv);
    }
}

// ---------------------------------------------------------------- launch
extern "C" void kernel_launch(void* const* d_in, const int* in_sizes, int n_in,
                              void* d_out, int out_size, void* d_ws, size_t ws_size,
                              hipStream_t stream) {
    (void)in_sizes; (void)n_in; (void)out_size; (void)ws_size;
    const float* x  = (const float*)d_in[0];
    const float* Wq = (const float*)d_in[2];
    const float* bq = (const float*)d_in[3];
    const float* Wk = (const float*)d_in[4];
    const float* bk = (const float*)d_in[5];
    const float* Wv = (const float*)d_in[6];
    const float* bv = (const float*)d_in[7];
    const float* Wo = (const float*)d_in[8];
    const float* bo = (const float*)d_in[9];
    float* out = (float*)d_out;

    // ws (40 MB): x_bf/O | Q | K | V^T | Wt x4
    char* ws = (char*)d_ws;
    unsigned short* xbf = (unsigned short*)(ws);
    unsigned short* qws = (unsigned short*)(ws + ((size_t)8  << 20));
    unsigned short* kws = (unsigned short*)(ws + ((size_t)16 << 20));
    unsigned short* vws = (unsigned short*)(ws + ((size_t)24 << 20));
    unsigned short* wt  = (unsigned short*)(ws + ((size_t)32 << 20));
    unsigned short* ows = xbf;   // O overwrites x_bf (dead after QKV GEMM)

    prep<<<dim3(5120), 256, 0, stream>>>(x, Wq, Wk, Wv, Wo, xbf, wt);
    gemm_qkv<<<dim3(24, 32), 256, 0, stream>>>(xbf, wt, bq, bk, bv,
                                               qws, kws, vws);
    attn<<<dim3(1024), 256, 0, stream>>>(qws, kws, vws, ows);
    gemm_out<<<dim3(16, 32), 256, 0, stream>>>(ows, wt + (size_t)3 * 1024 * 1024,
                                               bo, out);
}